// Round 1
// baseline (248.371 us; speedup 1.0000x reference)
//
#include <hip/hip_runtime.h>

#define NV  16
#define NB  64
#define NT  256
#define NH  128
#define NFC 256
#define NC  10

typedef _Float16 half8  __attribute__((ext_vector_type(8)));
typedef _Float16 half4t __attribute__((ext_vector_type(4)));
typedef float    f32x4  __attribute__((ext_vector_type(4)));

// One workgroup = one variable v, 16 batch rows. 8 waves.
// Per step: gh^T = Whh_slice(16n x 128k) * h^T(128k x 16b) via mfma 16x16x32 f16.
// Wave w owns gate-columns [w*16, w*16+16) of each of the 3 gates (tiles at
// n0 = g*128 + w*16). A-frags (Whh, fp16) live in registers for all 256 steps.
// B-frags (h^T, fp16) live in a double-buffered LDS fragment buffer.
// C layout (verified m89): col = lane&15 (batch row), row = (lane>>4)*4+reg
// (h-column). So each lane owns h[r][j0..j0+3] persistently -> h_old in regs.
__global__ __launch_bounds__(512, 2) void gru_scan_kernel(
    const float* __restrict__ x,   const float* __restrict__ Wih,
    const float* __restrict__ Whh, const float* __restrict__ bih,
    const float* __restrict__ bhh, const float* __restrict__ Wp,
    const float* __restrict__ bp,  float* __restrict__ concat_ws)
{
    __shared__ __align__(16) _Float16 frag[2][2048];  // 2 x 4KB: [kb*512 + lane*8]
    __shared__ float xT[NT][17];                      // x transposed, padded
    __shared__ float pc[8][16];

    const int tid = threadIdx.x;
    const int w   = tid >> 6;        // wave 0..7
    const int l   = tid & 63;
    const int r   = l & 15;          // batch row within chunk
    const int m4  = l >> 4;          // 0..3
    const int bid = blockIdx.x;
    const int v   = bid >> 2;        // variable
    const int b0  = (bid & 3) << 4;  // batch chunk base
    const int j0  = (w << 4) + (m4 << 2);  // this lane's h-column base (4 cols)

    // ---- stage x[v, b0+rr, :] into xT[t][rr] (one-time) ----
    {
        const int rr = tid >> 5;           // 0..15
        const int t0 = (tid & 31) << 3;    // 0..248
        const float* xp = x + ((size_t)(v * NB + b0 + rr) * NT + t0);
        float4 a = *(const float4*)xp;
        float4 b = *(const float4*)(xp + 4);
        xT[t0+0][rr] = a.x; xT[t0+1][rr] = a.y; xT[t0+2][rr] = a.z; xT[t0+3][rr] = a.w;
        xT[t0+4][rr] = b.x; xT[t0+5][rr] = b.y; xT[t0+6][rr] = b.z; xT[t0+7][rr] = b.w;
    }
    // zero h-frag buffer 0 (h0 = 0)
    ((unsigned long long*)(&frag[0][0]))[tid] = 0ull;

    // ---- preload Whh A-fragments: A[n = l&15][k = kb*32 + (l>>4)*8 + e] ----
    half8 afr[3][4];
    #pragma unroll
    for (int g = 0; g < 3; ++g) {
        #pragma unroll
        for (int kb = 0; kb < 4; ++kb) {
            const float* wpp = Whh + (size_t)(v * 384 + g * 128 + (w << 4) + r) * 128
                             + kb * 32 + m4 * 8;
            float4 lo = *(const float4*)wpp;
            float4 hi = *(const float4*)(wpp + 4);
            half8 hf;
            hf[0]=(_Float16)lo.x; hf[1]=(_Float16)lo.y; hf[2]=(_Float16)lo.z; hf[3]=(_Float16)lo.w;
            hf[4]=(_Float16)hi.x; hf[5]=(_Float16)hi.y; hf[6]=(_Float16)hi.z; hf[7]=(_Float16)hi.w;
            afr[g][kb] = hf;
        }
    }

    // per-lane gate-dim params for columns j0..j0+3 of each gate
    float wih_[3][4], bih_[3][4], bhh_[3][4];
    #pragma unroll
    for (int g = 0; g < 3; ++g) {
        #pragma unroll
        for (int q = 0; q < 4; ++q) {
            const int idx = v * 384 + g * 128 + j0 + q;
            wih_[g][q] = Wih[idx];
            bih_[g][q] = bih[idx];
            bhh_[g][q] = bhh[idx];
        }
    }
    float wpv[4];
    #pragma unroll
    for (int q = 0; q < 4; ++q) wpv[q] = Wp[v * NH + j0 + q];

    float h_old[4] = {0.f, 0.f, 0.f, 0.f};

    // frag-write offset: element (r, k0=j0) -> kb = j0>>5, lane' = r + 16*((j0&31)>>3),
    // elem = j0&7 in {0,4}. Linear across the wave -> conflict-free ds_write_b64.
    const int sub8  = (j0 & 31) >> 3;
    const int fwoff = (j0 >> 5) * 512 + (r + 16 * sub8) * 8 + (j0 & 7);
    const int rdoff = l * 8;

    __syncthreads();

    constexpr float L2E = 1.44269504088896340736f;

    auto step = [&](const _Float16* __restrict__ fb, _Float16* __restrict__ fwb,
                    const int t) {
        half8 bfr[4];
        #pragma unroll
        for (int kb = 0; kb < 4; ++kb)
            bfr[kb] = *(const half8*)(fb + kb * 512 + rdoff);
        const float xr = xT[t][r];
        f32x4 acc0 = {bhh_[0][0], bhh_[0][1], bhh_[0][2], bhh_[0][3]};
        f32x4 acc1 = {bhh_[1][0], bhh_[1][1], bhh_[1][2], bhh_[1][3]};
        f32x4 acc2 = {bhh_[2][0], bhh_[2][1], bhh_[2][2], bhh_[2][3]};
        #pragma unroll
        for (int kb = 0; kb < 4; ++kb) {
            acc0 = __builtin_amdgcn_mfma_f32_16x16x32_f16(afr[0][kb], bfr[kb], acc0, 0, 0, 0);
            acc1 = __builtin_amdgcn_mfma_f32_16x16x32_f16(afr[1][kb], bfr[kb], acc1, 0, 0, 0);
            acc2 = __builtin_amdgcn_mfma_f32_16x16x32_f16(afr[2][kb], bfr[kb], acc2, 0, 0, 0);
        }
        half4t hv;
        #pragma unroll
        for (int q = 0; q < 4; ++q) {
            const float sr = fmaf(xr, wih_[0][q], bih_[0][q]) + acc0[q];
            const float sz = fmaf(xr, wih_[1][q], bih_[1][q]) + acc1[q];
            const float gn = fmaf(xr, wih_[2][q], bih_[2][q]);
            const float rg = __builtin_amdgcn_rcpf(1.f + __builtin_amdgcn_exp2f(-L2E * sr));
            const float zg = __builtin_amdgcn_rcpf(1.f + __builtin_amdgcn_exp2f(-L2E * sz));
            const float cc = fmaf(rg, acc2[q], gn);  // i_n + r*(gh_n + bhh_n)
            const float th = 1.f - 2.f * __builtin_amdgcn_rcpf(
                                 1.f + __builtin_amdgcn_exp2f(2.f * L2E * cc));
            const float hn = fmaf(zg, h_old[q] - th, th);  // (1-z)n + z h
            h_old[q] = hn;
            hv[q] = (_Float16)hn;
        }
        *(half4t*)(fwb + fwoff) = hv;
        __syncthreads();
    };

    for (int t = 0; t < NT; t += 2) {
        step(&frag[0][0], &frag[1][0], t);
        step(&frag[1][0], &frag[0][0], t + 1);
    }

    // ---- epilogue: concat[b0+r][v] = dot(h_last[r,:], Wp[v,:]) + bp[v] ----
    float partial = h_old[0]*wpv[0] + h_old[1]*wpv[1] + h_old[2]*wpv[2] + h_old[3]*wpv[3];
    partial += __shfl_xor(partial, 16, 64);
    partial += __shfl_xor(partial, 32, 64);
    if (l < 16) pc[w][l] = partial;
    __syncthreads();
    if (tid < 16) {
        float s = bp[v];
        #pragma unroll
        for (int ww = 0; ww < 8; ++ww) s += pc[ww][tid];
        concat_ws[(b0 + tid) * NV + v] = s;
    }
}

// FC head: concat[64][16] -> relu(W1) -> W2 -> out[64][10]. One small block.
__global__ __launch_bounds__(256, 1) void fc_kernel(
    const float* __restrict__ cws, const float* __restrict__ W1,
    const float* __restrict__ b1,  const float* __restrict__ W2,
    const float* __restrict__ b2,  float* __restrict__ out)
{
    __shared__ float cc[NB][NV + 1];
    __shared__ float hfc[NB][NFC + 1];
    const int tid = threadIdx.x;
    for (int i = tid; i < NB * NV; i += 256) cc[i >> 4][i & 15] = cws[i];
    __syncthreads();

    float w1r[NV];
    #pragma unroll
    for (int q = 0; q < NV; q += 4) {
        float4 t4 = *(const float4*)(W1 + tid * NV + q);
        w1r[q] = t4.x; w1r[q+1] = t4.y; w1r[q+2] = t4.z; w1r[q+3] = t4.w;
    }
    const float bb = b1[tid];
    for (int b = 0; b < NB; ++b) {
        float s = bb;
        #pragma unroll
        for (int q = 0; q < NV; ++q) s = fmaf(cc[b][q], w1r[q], s);
        hfc[b][tid] = fmaxf(s, 0.f);
    }
    __syncthreads();

    for (int idx = tid; idx < NB * NC; idx += 256) {
        const int b = idx / NC, c = idx % NC;
        const float* w2r = W2 + c * NFC;
        float s = b2[c];
        #pragma unroll 4
        for (int f = 0; f < NFC; f += 4) {
            float4 wv = *(const float4*)(w2r + f);
            s = fmaf(hfc[b][f+0], wv.x, s);
            s = fmaf(hfc[b][f+1], wv.y, s);
            s = fmaf(hfc[b][f+2], wv.z, s);
            s = fmaf(hfc[b][f+3], wv.w, s);
        }
        out[idx] = s;
    }
}

extern "C" void kernel_launch(void* const* d_in, const int* in_sizes, int n_in,
                              void* d_out, int out_size, void* d_ws, size_t ws_size,
                              hipStream_t stream) {
    const float* x   = (const float*)d_in[0];
    const float* Wih = (const float*)d_in[1];
    const float* Whh = (const float*)d_in[2];
    const float* bih = (const float*)d_in[3];
    const float* bhh = (const float*)d_in[4];
    const float* Wp  = (const float*)d_in[5];
    const float* bp  = (const float*)d_in[6];
    const float* W1  = (const float*)d_in[7];
    const float* b1  = (const float*)d_in[8];
    const float* W2  = (const float*)d_in[9];
    const float* b2  = (const float*)d_in[10];
    float* out = (float*)d_out;
    float* cws = (float*)d_ws;  // concat scratch: 64*16 f32 = 4 KB

    gru_scan_kernel<<<dim3(64), dim3(512), 0, stream>>>(x, Wih, Whh, bih, bhh, Wp, bp, cws);
    fc_kernel<<<dim3(1), dim3(256), 0, stream>>>(cws, W1, b1, W2, b2, out);
}

// Round 2
// 240.926 us; speedup vs baseline: 1.0309x; 1.0309x over previous
//
#include <hip/hip_runtime.h>

#define NV  16
#define NB  64
#define NT  256
#define NH  128
#define NFC 256
#define NC  10

typedef _Float16 half8  __attribute__((ext_vector_type(8)));
typedef _Float16 half4t __attribute__((ext_vector_type(4)));
typedef float    f32x4  __attribute__((ext_vector_type(4)));

// One workgroup = one variable v, 16 batch rows. 8 waves.
// Per step: gh^T = Whh_slice(16n x 128k) * h^T(128k x 16b) via mfma 16x16x32 f16.
// Wave w owns h-columns [w*16, w*16+16) of each of the 3 gates. A-frags (Whh,
// fp16, PRESCALED by -log2e / +2log2e) live in registers for all 256 steps.
// B-frags (h^T, fp16) live in a double-buffered LDS fragment buffer.
// C layout (verified m89): col = lane&15 (batch row), row = (lane>>4)*4+reg
// (h-column). Each lane owns h[r][j0..j0+3] persistently -> h_old in regs.
//
// Activation algebra (division-minimized):
//   srs = -L2E*(i_r + gh_r + bhh_r)   -> r = rcp(1 + exp2(srs))
//   szs = -L2E*(i_z + gh_z + bhh_z)   -> a = exp2(szs); z = 1/(1+a)
//   ccs = 2L2E*(i_n + r*(gh_n+bhh_n)) -> b = exp2(-ccs); tanh = (1-b)/(1+b)
//   h'  = (1-z)*tanh + z*h = [a*(1-b) + h*(1+b)] / [(1+a)*(1+b)]
// All scale factors folded into the weights/biases at load time.
__global__ __launch_bounds__(512, 2) void gru_scan_kernel(
    const float* __restrict__ x,   const float* __restrict__ Wih,
    const float* __restrict__ Whh, const float* __restrict__ bih,
    const float* __restrict__ bhh, const float* __restrict__ Wp,
    const float* __restrict__ bp,  float* __restrict__ concat_ws)
{
    __shared__ __align__(16) _Float16 frag[2][2048];  // 2 x 4KB: [kb*512 + lane*8]
    __shared__ float xT[NT][17];                      // x transposed, padded
    __shared__ float pc[8][16];

    const int tid = threadIdx.x;
    const int w   = tid >> 6;        // wave 0..7
    const int l   = tid & 63;
    const int r   = l & 15;          // batch row within chunk
    const int m4  = l >> 4;          // 0..3
    const int bid = blockIdx.x;
    const int v   = bid >> 2;        // variable
    const int b0  = (bid & 3) << 4;  // batch chunk base
    const int j0  = (w << 4) + (m4 << 2);  // this lane's h-column base (4 cols)

    constexpr float L2E = 1.44269504088896340736f;
    const float SCL0 = -L2E, SCL1 = -L2E, SCL2 = 2.0f * L2E;

    // ---- stage x[v, b0+rr, :] into xT[t][rr] (one-time) ----
    {
        const int rr = tid >> 5;           // 0..15
        const int t0 = (tid & 31) << 3;    // 0..248
        const float* xp = x + ((size_t)(v * NB + b0 + rr) * NT + t0);
        float4 a = *(const float4*)xp;
        float4 b = *(const float4*)(xp + 4);
        xT[t0+0][rr] = a.x; xT[t0+1][rr] = a.y; xT[t0+2][rr] = a.z; xT[t0+3][rr] = a.w;
        xT[t0+4][rr] = b.x; xT[t0+5][rr] = b.y; xT[t0+6][rr] = b.z; xT[t0+7][rr] = b.w;
    }
    // zero h-frag buffer 0 (h0 = 0)
    ((unsigned long long*)(&frag[0][0]))[tid] = 0ull;

    // ---- preload PRESCALED Whh A-fragments ----
    // A[n = l&15][k = kb*32 + (l>>4)*8 + e], scaled per gate.
    half8 afr[3][4];
    #pragma unroll
    for (int g = 0; g < 3; ++g) {
        const float s = (g == 2) ? SCL2 : SCL0;
        #pragma unroll
        for (int kb = 0; kb < 4; ++kb) {
            const float* wpp = Whh + (size_t)(v * 384 + g * 128 + (w << 4) + r) * 128
                             + kb * 32 + m4 * 8;
            float4 lo = *(const float4*)wpp;
            float4 hi = *(const float4*)(wpp + 4);
            half8 hf;
            hf[0]=(_Float16)(s*lo.x); hf[1]=(_Float16)(s*lo.y);
            hf[2]=(_Float16)(s*lo.z); hf[3]=(_Float16)(s*lo.w);
            hf[4]=(_Float16)(s*hi.x); hf[5]=(_Float16)(s*hi.y);
            hf[6]=(_Float16)(s*hi.z); hf[7]=(_Float16)(s*hi.w);
            afr[g][kb] = hf;
        }
    }

    // per-lane prescaled gate params for h-columns j0..j0+3 of each gate
    float wihs_[3][4], bihs_[3][4];
    f32x4 c0i, c1i, c2i;   // MFMA C-init vectors = prescaled bhh
    #pragma unroll
    for (int g = 0; g < 3; ++g) {
        const float s = (g == 2) ? SCL2 : SCL0;
        #pragma unroll
        for (int q = 0; q < 4; ++q) {
            const int idx = v * 384 + g * 128 + j0 + q;
            wihs_[g][q] = s * Wih[idx];
            bihs_[g][q] = s * bih[idx];
            const float bs = s * bhh[idx];
            if (g == 0) c0i[q] = bs; else if (g == 1) c1i[q] = bs; else c2i[q] = bs;
        }
    }
    float wpv[4];
    #pragma unroll
    for (int q = 0; q < 4; ++q) wpv[q] = Wp[v * NH + j0 + q];

    float h_old[4] = {0.f, 0.f, 0.f, 0.f};

    // frag-write offset: element (r, k0=j0) -> linear across wave, conflict-free.
    const int sub8  = (j0 & 31) >> 3;
    const int fwoff = (j0 >> 5) * 512 + (r + 16 * sub8) * 8 + (j0 & 7);
    const int rdoff = l * 8;

    __syncthreads();

    auto step = [&](const _Float16* __restrict__ fb, _Float16* __restrict__ fwb,
                    const float xr) {
        half8 bfr[4];
        #pragma unroll
        for (int kb = 0; kb < 4; ++kb)
            bfr[kb] = *(const half8*)(fb + kb * 512 + rdoff);

        // three accumulator chains; C-init = prescaled bhh (no movs)
        f32x4 acc0 = __builtin_amdgcn_mfma_f32_16x16x32_f16(afr[0][0], bfr[0], c0i, 0, 0, 0);
        f32x4 acc1 = __builtin_amdgcn_mfma_f32_16x16x32_f16(afr[1][0], bfr[0], c1i, 0, 0, 0);
        f32x4 acc2 = __builtin_amdgcn_mfma_f32_16x16x32_f16(afr[2][0], bfr[0], c2i, 0, 0, 0);
        #pragma unroll
        for (int kb = 1; kb < 4; ++kb) {
            acc0 = __builtin_amdgcn_mfma_f32_16x16x32_f16(afr[0][kb], bfr[kb], acc0, 0, 0, 0);
            acc1 = __builtin_amdgcn_mfma_f32_16x16x32_f16(afr[1][kb], bfr[kb], acc1, 0, 0, 0);
            acc2 = __builtin_amdgcn_mfma_f32_16x16x32_f16(afr[2][kb], bfr[kb], acc2, 0, 0, 0);
        }

        // pass A: r-gate sigma and z-gate exp (depend on acc0/acc1 only;
        // scheduler overlaps these trans ops with the acc2 MFMA chain)
        float rg[4], av[4];
        #pragma unroll
        for (int q = 0; q < 4; ++q) {
            const float srs = fmaf(xr, wihs_[0][q], bihs_[0][q]) + acc0[q];
            const float szs = fmaf(xr, wihs_[1][q], bihs_[1][q]) + acc1[q];
            rg[q] = __builtin_amdgcn_rcpf(1.f + __builtin_amdgcn_exp2f(srs));
            av[q] = __builtin_amdgcn_exp2f(szs);
        }
        // pass B: n-gate + state update, single rcp for (1+a)(1+b)
        half4t hv;
        #pragma unroll
        for (int q = 0; q < 4; ++q) {
            const float gns = fmaf(xr, wihs_[2][q], bihs_[2][q]);
            const float ccs = fmaf(rg[q], acc2[q], gns);
            const float b   = __builtin_amdgcn_exp2f(-ccs);
            const float a   = av[q];
            const float h   = h_old[q];
            const float num = fmaf(-a, b, a) + fmaf(h, b, h);   // a(1-b) + h(1+b)
            const float den = (1.f + a) * (1.f + b);
            const float hn  = num * __builtin_amdgcn_rcpf(den);
            h_old[q] = hn;
            hv[q] = (_Float16)hn;
        }
        *(half4t*)(fwb + fwoff) = hv;
        __syncthreads();
    };

    for (int t = 0; t < NT; t += 2) {
        const float xa = xT[t][r];
        const float xb = xT[t + 1][r];
        step(&frag[0][0], &frag[1][0], xa);
        step(&frag[1][0], &frag[0][0], xb);
    }

    // ---- epilogue: concat[b0+r][v] = dot(h_last[r,:], Wp[v,:]) + bp[v] ----
    float partial = h_old[0]*wpv[0] + h_old[1]*wpv[1] + h_old[2]*wpv[2] + h_old[3]*wpv[3];
    partial += __shfl_xor(partial, 16, 64);
    partial += __shfl_xor(partial, 32, 64);
    if (l < 16) pc[w][l] = partial;
    __syncthreads();
    if (tid < 16) {
        float s = bp[v];
        #pragma unroll
        for (int ww = 0; ww < 8; ++ww) s += pc[ww][tid];
        concat_ws[(b0 + tid) * NV + v] = s;
    }
}

// FC head: concat[64][16] -> relu(W1) -> W2 -> out[64][10]. One small block.
__global__ __launch_bounds__(256, 1) void fc_kernel(
    const float* __restrict__ cws, const float* __restrict__ W1,
    const float* __restrict__ b1,  const float* __restrict__ W2,
    const float* __restrict__ b2,  float* __restrict__ out)
{
    __shared__ float cc[NB][NV + 1];
    __shared__ float hfc[NB][NFC + 1];
    const int tid = threadIdx.x;
    for (int i = tid; i < NB * NV; i += 256) cc[i >> 4][i & 15] = cws[i];
    __syncthreads();

    float w1r[NV];
    #pragma unroll
    for (int q = 0; q < NV; q += 4) {
        float4 t4 = *(const float4*)(W1 + tid * NV + q);
        w1r[q] = t4.x; w1r[q+1] = t4.y; w1r[q+2] = t4.z; w1r[q+3] = t4.w;
    }
    const float bb = b1[tid];
    for (int b = 0; b < NB; ++b) {
        float s = bb;
        #pragma unroll
        for (int q = 0; q < NV; ++q) s = fmaf(cc[b][q], w1r[q], s);
        hfc[b][tid] = fmaxf(s, 0.f);
    }
    __syncthreads();

    for (int idx = tid; idx < NB * NC; idx += 256) {
        const int b = idx / NC, c = idx % NC;
        const float* w2r = W2 + c * NFC;
        float s = b2[c];
        #pragma unroll 4
        for (int f = 0; f < NFC; f += 4) {
            float4 wv = *(const float4*)(w2r + f);
            s = fmaf(hfc[b][f+0], wv.x, s);
            s = fmaf(hfc[b][f+1], wv.y, s);
            s = fmaf(hfc[b][f+2], wv.z, s);
            s = fmaf(hfc[b][f+3], wv.w, s);
        }
        out[idx] = s;
    }
}

extern "C" void kernel_launch(void* const* d_in, const int* in_sizes, int n_in,
                              void* d_out, int out_size, void* d_ws, size_t ws_size,
                              hipStream_t stream) {
    const float* x   = (const float*)d_in[0];
    const float* Wih = (const float*)d_in[1];
    const float* Whh = (const float*)d_in[2];
    const float* bih = (const float*)d_in[3];
    const float* bhh = (const float*)d_in[4];
    const float* Wp  = (const float*)d_in[5];
    const float* bp  = (const float*)d_in[6];
    const float* W1  = (const float*)d_in[7];
    const float* b1  = (const float*)d_in[8];
    const float* W2  = (const float*)d_in[9];
    const float* b2  = (const float*)d_in[10];
    float* out = (float*)d_out;
    float* cws = (float*)d_ws;  // concat scratch: 64*16 f32 = 4 KB

    gru_scan_kernel<<<dim3(64), dim3(512), 0, stream>>>(x, Wih, Whh, bih, bhh, Wp, bp, cws);
    fc_kernel<<<dim3(1), dim3(256), 0, stream>>>(cws, W1, b1, W2, b2, out);
}